// Round 13
// baseline (144.069 us; speedup 1.0000x reference)
//
#include <hip/hip_runtime.h>

// LinearAttentionSVAR: B=2, L=2048, D=1024, H=16, d=64.
// Round 13: revert r12; 5 launches via last-finisher merge (no spin, no coop):
//  prep -> qkv (zeroes ctr) -> state_pf(state 512 + fold 128; last finisher of
//  each bh group runs that bh's exclusive prefix after device-scope fence+atomic)
//  -> attn -> out. All compute bodies are round-10 verbatim.

#define DEV static __device__ __forceinline__

typedef unsigned short u16;
typedef unsigned long long u64;
typedef __attribute__((ext_vector_type(4))) float f32x4;
typedef __attribute__((ext_vector_type(8))) short bf16x8;

DEV u16 f2bf(float f){
  union { float f; unsigned u; } v; v.f = f;
  unsigned r = v.u + 0x7FFFu + ((v.u >> 16) & 1u);
  return (u16)(r >> 16);
}

DEV void store_val(float* p, float v){ *p = v; }
DEV void store_val(u16* p, float v){ *p = f2bf(v); }

DEV void gload16(const void* g, void* l){
  __builtin_amdgcn_global_load_lds((const __attribute__((address_space(1))) void*)g,
                                   (__attribute__((address_space(3))) void*)l, 16, 0, 0);
}

// ---------------- 1. prep: bf16 converts + per-head Bm ----------------
__global__ __launch_bounds__(256) void prep_kernel(
    const float* __restrict__ X, u16* __restrict__ Xb,
    const float* __restrict__ Wq, u16* __restrict__ Wqb,
    const float* __restrict__ Wk, u16* __restrict__ Wkb,
    const float* __restrict__ Wv, u16* __restrict__ Wvb,
    const float* __restrict__ Wc, u16* __restrict__ Wcb,
    const float* __restrict__ Ltri, u16* __restrict__ Bmb)
{
  const int bx = blockIdx.x, tid = threadIdx.x;
  if(bx < 16){
    __shared__ float Lm[64][65];
    int h = bx;
    const float* src = Ltri + (size_t)h * 4096;
    for(int i = tid; i < 4096; i += 256){
      int e = i >> 6, k = i & 63;
      Lm[e][k] = (k <= e) ? src[i] : 0.f;
    }
    __syncthreads();
    u16* out = Bmb + (size_t)h * 4096;
    for(int i = tid; i < 4096; i += 256){
      int e = i >> 6, dk = i & 63;
      float sum = 0.f;
      int kmax = e < dk ? e : dk;
      for(int k = 0; k <= kmax; k++) sum += Lm[e][k] * Lm[dk][k];
      out[i] = f2bf(sum);
    }
  } else {
    const int n0 = 4194304, n1 = 1048576, n2 = 1048576, n3 = 1048576, n4 = 1048576;
    int total = (n0 + n1 + n2 + n3 + n4) >> 2;
    for(int i = (bx - 16) * 256 + tid; i < total; i += 2048 * 256){
      int e = i << 2;
      const float* s; u16* d;
      if(e < n0){ s = X + e; d = Xb + e; }
      else if(e < n0 + n1){ s = Wq + (e - n0); d = Wqb + (e - n0); }
      else if(e < n0 + n1 + n2){ s = Wk + (e - n0 - n1); d = Wkb + (e - n0 - n1); }
      else if(e < n0 + n1 + n2 + n3){ s = Wv + (e - n0 - n1 - n2); d = Wvb + (e - n0 - n1 - n2); }
      else { s = Wc + (e - n0 - n1 - n2 - n3); d = Wcb + (e - n0 - n1 - n2 - n3); }
      float4 v = *(const float4*)s;
      u64 pk = (u64)f2bf(v.x) | ((u64)f2bf(v.y) << 16) | ((u64)f2bf(v.z) << 32) | ((u64)f2bf(v.w) << 48);
      *(u64*)d = pk;
    }
  }
}

// ---------------- GEMM tile body: BK=32, row-pair-fused swizzle, depth-2 ----------------
template<typename OutT>
DEV void gemm128_p2(const u16* __restrict__ A, const u16* __restrict__ W,
                    OutT* __restrict__ C, int bx, int by, int N, int K)
{
  __shared__ u16 L[3][8192];
  const int tid = threadIdx.x;
  const int wid = tid >> 6, lane = tid & 63;
  const int wr = wid >> 1, wc = wid & 1;
  const int lr = lane & 15, lq = lane >> 4;
  const u16* Ag = A + (size_t)(bx * 128) * K;
  const u16* Wg = W + (size_t)(by * 128) * K;

  const int p0 = tid >> 3, p1 = 32 + (tid >> 3);
  const int cl0 = (tid & 7) ^ (p0 & 7);
  const int cl1 = (tid & 7) ^ (p1 & 7);
  const int srow0 = 2 * p0 + (cl0 >> 2), skc0 = (cl0 & 3) * 8;
  const int srow1 = 2 * p1 + (cl1 >> 2), skc1 = (cl1 & 3) * 8;

  auto stagef = [&](int kt, int buf){
    gload16(Ag + (size_t)srow0 * K + kt * 32 + skc0, &L[buf][tid * 8]);
    gload16(Ag + (size_t)srow1 * K + kt * 32 + skc1, &L[buf][2048 + tid * 8]);
    gload16(Wg + (size_t)srow0 * K + kt * 32 + skc0, &L[buf][4096 + tid * 8]);
    gload16(Wg + (size_t)srow1 * K + kt * 32 + skc1, &L[buf][6144 + tid * 8]);
  };

  const int nt = K >> 5;
  f32x4 acc[4][4] = {};
  stagef(0, 0);
  stagef(1, 1);
  int cur = 0;
  for(int t = 0; t < nt; t++){
    if(t < nt - 1) asm volatile("s_waitcnt vmcnt(4)" ::: "memory");
    else           asm volatile("s_waitcnt vmcnt(0)" ::: "memory");
    __builtin_amdgcn_s_barrier();
    __builtin_amdgcn_sched_barrier(0);
    if(t + 2 < nt){
      int n2 = cur >= 1 ? cur - 1 : cur + 2;
      stagef(t + 2, n2);
    }
    const u16* Lb = L[cur];
    bf16x8 af[4], bfr[4];
#pragma unroll
    for(int i = 0; i < 4; i++){
      int row = wr * 64 + i * 16 + lr;
      int rh = row >> 1;
      int cph = (lq | ((row & 1) << 2)) ^ (rh & 7);
      af[i] = *(const bf16x8*)&Lb[rh * 64 + cph * 8];
    }
#pragma unroll
    for(int j = 0; j < 4; j++){
      int row = wc * 64 + j * 16 + lr;
      int rh = row >> 1;
      int cph = (lq | ((row & 1) << 2)) ^ (rh & 7);
      bfr[j] = *(const bf16x8*)&Lb[4096 + rh * 64 + cph * 8];
    }
#pragma unroll
    for(int i = 0; i < 4; i++)
#pragma unroll
      for(int j = 0; j < 4; j++)
        acc[i][j] = __builtin_amdgcn_mfma_f32_16x16x32_bf16(af[i], bfr[j], acc[i][j], 0, 0, 0);
    cur = cur == 2 ? 0 : cur + 1;
  }
#pragma unroll
  for(int i = 0; i < 4; i++)
#pragma unroll
    for(int j = 0; j < 4; j++)
#pragma unroll
      for(int r = 0; r < 4; r++){
        int row = bx * 128 + wr * 64 + i * 16 + lq * 4 + r;
        int col = by * 128 + wc * 64 + j * 16 + lr;
        store_val(C + (size_t)row * N + col, acc[i][j][r]);
      }
}

// ---------------- depth-3 variant (4 bufs) for 1-block/CU out_gemm ----------------
template<typename OutT>
DEV void gemm128_p3(const u16* __restrict__ A, const u16* __restrict__ W,
                    OutT* __restrict__ C, int bx, int by, int N, int K)
{
  __shared__ u16 L[4][8192];
  const int tid = threadIdx.x;
  const int wid = tid >> 6, lane = tid & 63;
  const int wr = wid >> 1, wc = wid & 1;
  const int lr = lane & 15, lq = lane >> 4;
  const u16* Ag = A + (size_t)(bx * 128) * K;
  const u16* Wg = W + (size_t)(by * 128) * K;

  const int p0 = tid >> 3, p1 = 32 + (tid >> 3);
  const int cl0 = (tid & 7) ^ (p0 & 7);
  const int cl1 = (tid & 7) ^ (p1 & 7);
  const int srow0 = 2 * p0 + (cl0 >> 2), skc0 = (cl0 & 3) * 8;
  const int srow1 = 2 * p1 + (cl1 >> 2), skc1 = (cl1 & 3) * 8;

  auto stagef = [&](int kt, int buf){
    gload16(Ag + (size_t)srow0 * K + kt * 32 + skc0, &L[buf][tid * 8]);
    gload16(Ag + (size_t)srow1 * K + kt * 32 + skc1, &L[buf][2048 + tid * 8]);
    gload16(Wg + (size_t)srow0 * K + kt * 32 + skc0, &L[buf][4096 + tid * 8]);
    gload16(Wg + (size_t)srow1 * K + kt * 32 + skc1, &L[buf][6144 + tid * 8]);
  };

  const int nt = K >> 5;
  f32x4 acc[4][4] = {};
  stagef(0, 0);
  stagef(1, 1);
  stagef(2, 2);
  for(int t = 0; t < nt; t++){
    if(t < nt - 2)       asm volatile("s_waitcnt vmcnt(8)" ::: "memory");
    else if(t == nt - 2) asm volatile("s_waitcnt vmcnt(4)" ::: "memory");
    else                 asm volatile("s_waitcnt vmcnt(0)" ::: "memory");
    __builtin_amdgcn_s_barrier();
    __builtin_amdgcn_sched_barrier(0);
    if(t + 3 < nt) stagef(t + 3, (t + 3) & 3);
    const u16* Lb = L[t & 3];
    bf16x8 af[4], bfr[4];
#pragma unroll
    for(int i = 0; i < 4; i++){
      int row = wr * 64 + i * 16 + lr;
      int rh = row >> 1;
      int cph = (lq | ((row & 1) << 2)) ^ (rh & 7);
      af[i] = *(const bf16x8*)&Lb[rh * 64 + cph * 8];
    }
#pragma unroll
    for(int j = 0; j < 4; j++){
      int row = wc * 64 + j * 16 + lr;
      int rh = row >> 1;
      int cph = (lq | ((row & 1) << 2)) ^ (rh & 7);
      bfr[j] = *(const bf16x8*)&Lb[4096 + rh * 64 + cph * 8];
    }
#pragma unroll
    for(int i = 0; i < 4; i++)
#pragma unroll
      for(int j = 0; j < 4; j++)
        acc[i][j] = __builtin_amdgcn_mfma_f32_16x16x32_bf16(af[i], bfr[j], acc[i][j], 0, 0, 0);
  }
#pragma unroll
  for(int i = 0; i < 4; i++)
#pragma unroll
    for(int j = 0; j < 4; j++)
#pragma unroll
      for(int r = 0; r < 4; r++){
        int row = bx * 128 + wr * 64 + i * 16 + lq * 4 + r;
        int col = by * 128 + wc * 64 + j * 16 + lr;
        store_val(C + (size_t)row * N + col, acc[i][j][r]);
      }
}

// ---------------- qkv: pure GEMM (768 blocks = 3.0/CU) + ctr zeroing ----------------
__global__ __launch_bounds__(256) void qkv_gemm(
    const u16* __restrict__ Xb,
    const u16* __restrict__ Wq, const u16* __restrict__ Wk, const u16* __restrict__ Wv,
    u16* __restrict__ Q, u16* __restrict__ Ko, u16* __restrict__ V,
    unsigned* __restrict__ ctr)
{
  if(blockIdx.x == 0 && blockIdx.y == 0 && threadIdx.x < 32) ctr[threadIdx.x] = 0u;
  int sel = blockIdx.y >> 3, byl = blockIdx.y & 7;
  const u16* W = sel == 0 ? Wq : sel == 1 ? Wk : Wv;
  u16* C = sel == 0 ? Q : sel == 1 ? Ko : V;
  gemm128_p2<u16>(Xb, W, C, blockIdx.x, byl, 1024, 1024);
}

__global__ __launch_bounds__(256) void out_gemm(
    const u16* __restrict__ Yb, const u16* __restrict__ Wcpb, float* __restrict__ out)
{
  gemm128_p3<float>(Yb, Wcpb, out, blockIdx.x, blockIdx.y, 1024, 1024);
}

// ---------------- state_pf: state (512) + fold (128); last finisher per bh
// group runs the exclusive prefix for that bh (device-scope fence + atomic) ----
__global__ __launch_bounds__(256) void state_pf(
    const u16* __restrict__ Kb, const u16* __restrict__ Vb,
    u16* __restrict__ VT, float* __restrict__ Sc, u16* __restrict__ Scb,
    const u16* __restrict__ Wcb, const u16* __restrict__ Bmb, u16* __restrict__ Wcpb,
    unsigned* __restrict__ ctr)
{
  const int bxg = blockIdx.x, tid = threadIdx.x;
  if(bxg >= 512){
    // Wc' fold
    int ob = bxg - 512;
    int rt = ob & 7, h = ob >> 3;
    int wid = tid >> 6, lane = tid & 63;
    int lr = lane & 15, lk8 = (lane >> 4) * 8, lq = lane >> 4;
    const u16* ab  = Wcb + (size_t)(rt * 128) * 1024 + h * 64;
    const u16* bm  = Bmb + (size_t)h * 4096;
    f32x4 acc[2][4] = {};
#pragma unroll
    for(int i = 0; i < 2; i++){
      int mf = wid * 2 + i;
#pragma unroll
      for(int ks = 0; ks < 2; ks++){
        bf16x8 a = *(const bf16x8*)(ab + (size_t)(mf * 16 + lr) * 1024 + ks * 32 + lk8);
#pragma unroll
        for(int nf = 0; nf < 4; nf++){
          bf16x8 bfr = *(const bf16x8*)(bm + (nf * 16 + lr) * 64 + ks * 32 + lk8);
          acc[i][nf] = __builtin_amdgcn_mfma_f32_16x16x32_bf16(a, bfr, acc[i][nf], 0, 0, 0);
        }
      }
    }
#pragma unroll
    for(int i = 0; i < 2; i++)
#pragma unroll
      for(int nf = 0; nf < 4; nf++)
#pragma unroll
        for(int r = 0; r < 4; r++){
          int row = rt * 128 + (wid * 2 + i) * 16 + lq * 4 + r;
          int col = h * 64 + nf * 16 + lr;
          Wcpb[(size_t)row * 1024 + col] = f2bf(acc[i][nf][r]);
        }
    return;
  }

  // ---- state body (round-10 v2) ----
  int bh = bxg >> 4, c = bxg & 15;
  int b = bh >> 4, h = bh & 15;
  __shared__ u16 Kt[128][72];
  __shared__ u16 Vt[128][72];
  __shared__ u16 KtT[64][136];
  __shared__ u16 VtT[64][136];
  __shared__ int sflag;
  int rr = tid >> 3;
  int cc = (tid & 7) * 8;
  const u16* kg = Kb + (size_t)(b * 2048 + c * 128) * 1024 + h * 64;
  const u16* vg = Vb + (size_t)(b * 2048 + c * 128) * 1024 + h * 64;
#pragma unroll
  for(int p = 0; p < 4; p++){
    int row = rr + p * 32;
    *(int4*)&Kt[row][cc] = *(const int4*)(kg + (size_t)row * 1024 + cc);
    *(int4*)&Vt[row][cc] = *(const int4*)(vg + (size_t)row * 1024 + cc);
  }
  __syncthreads();
  int d = tid >> 2, tseg = (tid & 3) * 32;
#pragma unroll
  for(int j = 0; j < 32; j += 8){
    u16 tk[8] __attribute__((aligned(16)));
    u16 tv[8] __attribute__((aligned(16)));
#pragma unroll
    for(int q = 0; q < 8; q++){
      tk[q] = Kt[tseg + j + q][d];
      tv[q] = Vt[tseg + j + q][d];
    }
    *(int4*)&KtT[d][tseg + j] = *(const int4*)tk;
    *(int4*)&VtT[d][tseg + j] = *(const int4*)tv;
  }
  __syncthreads();
  {
    u16* vto = VT + (size_t)bh * 64 * 2048 + (size_t)d * 2048 + c * 128 + tseg;
#pragma unroll
    for(int j = 0; j < 32; j += 8)
      *(int4*)(vto + j) = *(const int4*)&VtT[d][tseg + j];
  }
  int wid = tid >> 6, lane = tid & 63;
  int wr = wid >> 1, wc = wid & 1;
  int lr = lane & 15, lk8 = (lane >> 4) * 8, lq = lane >> 4;
  f32x4 acc[2][2] = {};
#pragma unroll
  for(int ks = 0; ks < 4; ks++){
    bf16x8 a[2], bb[2];
#pragma unroll
    for(int i = 0; i < 2; i++) a[i]  = *(const bf16x8*)&VtT[wr * 32 + i * 16 + lr][ks * 32 + lk8];
#pragma unroll
    for(int j = 0; j < 2; j++) bb[j] = *(const bf16x8*)&KtT[wc * 32 + j * 16 + lr][ks * 32 + lk8];
#pragma unroll
    for(int i = 0; i < 2; i++)
#pragma unroll
      for(int j = 0; j < 2; j++)
        acc[i][j] = __builtin_amdgcn_mfma_f32_16x16x32_bf16(a[i], bb[j], acc[i][j], 0, 0, 0);
  }
  float* outp = Sc + ((size_t)bh * 16 + c) * 4096;
#pragma unroll
  for(int i = 0; i < 2; i++)
#pragma unroll
    for(int j = 0; j < 2; j++)
#pragma unroll
      for(int r = 0; r < 4; r++){
        int e = wr * 32 + i * 16 + lq * 4 + r, dk = wc * 32 + j * 16 + lr;
        outp[e * 64 + dk] = acc[i][j][r];
      }

  // ---- last-finisher prefix for this bh group ----
  __syncthreads();                    // drains all Sc stores of this block
  if(tid == 0){
    __threadfence();                  // release: make Sc writes device-visible
    unsigned old = atomicAdd(&ctr[bh], 1u);
    sflag = (old == 15u);
  }
  __syncthreads();
  if(sflag){
    __threadfence();                  // acquire: see other blocks' Sc writes
    const float* sb = Sc + (size_t)bh * 65536;
    u16* db = Scb + (size_t)bh * 65536;
#pragma unroll
    for(int p = 0; p < 4; p++){
      int e4 = p * 256 + tid;
      const float4* s = (const float4*)sb + e4;
      u16* dp = db + e4 * 4;
      float4 run = {0.f, 0.f, 0.f, 0.f};
      for(int c2 = 0; c2 < 16; c2++){
        float4 v = s[(size_t)c2 * 1024];
        u64 pk = (u64)f2bf(run.x) | ((u64)f2bf(run.y) << 16) | ((u64)f2bf(run.z) << 32) | ((u64)f2bf(run.w) << 48);
        *(u64*)(dp + (size_t)c2 * 4096) = pk;
        run.x += v.x; run.y += v.y; run.z += v.z; run.w += v.w;
      }
    }
  }
}

// ---------------- chunk_attn (round-10 verbatim) ----------------
__global__ __launch_bounds__(256) void chunk_attn(
    const u16* __restrict__ Q, const u16* __restrict__ Kmat,
    const u16* __restrict__ VT, const u16* __restrict__ Scb, u16* __restrict__ Y)
{
  int bh = blockIdx.x, c = blockIdx.y;
  int b = bh >> 4, h = bh & 15;
  int t = threadIdx.x, wid = t >> 6, lane = t & 63;
  int lr = lane & 15, lk8 = (lane >> 4) * 8, lq = lane >> 4;
  __shared__ u16 S[128 * 128];
  const u16* qg = Q    + (size_t)(b * 2048 + c * 128) * 1024 + h * 64;
  const u16* kg = Kmat + (size_t)(b * 2048 + c * 128) * 1024 + h * 64;
  const u16* scb = Scb + ((size_t)bh * 16 + c) * 4096;
  const u16* vt  = VT + (size_t)bh * 64 * 2048 + (size_t)c * 128;
  u16* yg = Y + (size_t)(b * 2048 + c * 128) * 1024 + h * 64;

  bf16x8 a[2][2];
#pragma unroll
  for(int mi = 0; mi < 2; mi++){
    int mf = wid + mi * 4;
    int Rm = mf * 16;
    if((mf & 1) == 0){
      int zr = Rm + (lane >> 2), zc = Rm + 16 + (lane & 3) * 4;
      int zoff = ((zr * 128 + zc) * 2) ^ ((zr & 7) << 4);
      *(u64*)((char*)S + zoff) = 0ULL;
    }
#pragma unroll
    for(int ks = 0; ks < 2; ks++) a[mi][ks] = *(const bf16x8*)(qg + (size_t)(Rm + lr) * 1024 + ks * 32 + lk8);
    for(int nf = 0; nf <= mf; nf++){
      f32x4 acc = {};
#pragma unroll
      for(int ks = 0; ks < 2; ks++){
        bf16x8 bb = *(const bf16x8*)(kg + (size_t)(nf * 16 + lr) * 1024 + ks * 32 + lk8);
        acc = __builtin_amdgcn_mfma_f32_16x16x32_bf16(a[mi][ks], bb, acc, 0, 0, 0);
      }
#pragma unroll
      for(int r = 0; r < 4; r++){
        int row = lq * 4 + r, col = lr;
        float v = acc[r];
        if(nf == mf && col > row) v = 0.f;
        int grow = Rm + row, gcol = nf * 16 + col;
        int off = ((grow * 128 + gcol) * 2) ^ ((grow & 7) << 4);
        *(u16*)((char*)S + off) = f2bf(v);
      }
    }
  }
  f32x4 acc2[2][4] = {};
#pragma unroll
  for(int nf = 0; nf < 4; nf++)
#pragma unroll
    for(int ks = 0; ks < 2; ks++){
      bf16x8 bb = *(const bf16x8*)(scb + (nf * 16 + lr) * 64 + ks * 32 + lk8);
#pragma unroll
      for(int mi = 0; mi < 2; mi++)
        acc2[mi][nf] = __builtin_amdgcn_mfma_f32_16x16x32_bf16(a[mi][ks], bb, acc2[mi][nf], 0, 0, 0);
    }
  int ks0 = wid >> 1;
  int row0 = wid * 16 + lr;
  int row1 = (wid + 4) * 16 + lr;
  for(int ks = 0; ks <= ks0 + 2; ks++){
    bf16x8 bb[4];
#pragma unroll
    for(int nf = 0; nf < 4; nf++)
      bb[nf] = *(const bf16x8*)(vt + (size_t)(nf * 16 + lr) * 2048 + ks * 32 + lk8);
    if(ks <= ks0){
      int off = ((row0 * 128 + ks * 32 + lk8) * 2) ^ ((row0 & 7) << 4);
      bf16x8 af = *(const bf16x8*)((char*)S + off);
#pragma unroll
      for(int nf = 0; nf < 4; nf++)
        acc2[0][nf] = __builtin_amdgcn_mfma_f32_16x16x32_bf16(af, bb[nf], acc2[0][nf], 0, 0, 0);
    }
    {
      int off = ((row1 * 128 + ks * 32 + lk8) * 2) ^ ((row1 & 7) << 4);
      bf16x8 af = *(const bf16x8*)((char*)S + off);
#pragma unroll
      for(int nf = 0; nf < 4; nf++)
        acc2[1][nf] = __builtin_amdgcn_mfma_f32_16x16x32_bf16(af, bb[nf], acc2[1][nf], 0, 0, 0);
    }
  }
#pragma unroll
  for(int mi = 0; mi < 2; mi++){
    int Rm = (wid + mi * 4) * 16;
#pragma unroll
    for(int nf = 0; nf < 4; nf++)
#pragma unroll
      for(int r = 0; r < 4; r++){
        int grow = Rm + lq * 4 + r, gcol = nf * 16 + lr;
        yg[(size_t)grow * 1024 + gcol] = f2bf(acc2[mi][nf][r]);
      }
  }
}

// ---------------- launch ----------------
extern "C" void kernel_launch(void* const* d_in, const int* in_sizes, int n_in,
                              void* d_out, int out_size, void* d_ws, size_t ws_size,
                              hipStream_t stream)
{
  const float* X    = (const float*)d_in[0];
  const float* Wq   = (const float*)d_in[1];
  const float* Wk   = (const float*)d_in[2];
  const float* Wv   = (const float*)d_in[3];
  const float* Wc   = (const float*)d_in[4];
  const float* Ltri = (const float*)d_in[5];
  float* out = (float*)d_out;

  char* ws = (char*)d_ws;
  size_t off = 0;
  auto carve = [&](size_t bytes) -> char* {
    char* p = ws + off;
    off += (bytes + 255) & ~(size_t)255;
    return p;
  };
  u16* Xb   = (u16*)carve((size_t)4194304 * 2);
  u16* Wqb  = (u16*)carve((size_t)1048576 * 2);
  u16* Wkb  = (u16*)carve((size_t)1048576 * 2);
  u16* Wvb  = (u16*)carve((size_t)1048576 * 2);
  u16* Wcb  = (u16*)carve((size_t)1048576 * 2);
  u16* Wcpb = (u16*)carve((size_t)1048576 * 2);
  u16* Bmb  = (u16*)carve((size_t)65536 * 2);
  u16* Qb   = (u16*)carve((size_t)4194304 * 2);
  u16* Kb   = (u16*)carve((size_t)4194304 * 2);
  u16* Vb   = (u16*)carve((size_t)4194304 * 2);
  u16* VT   = (u16*)carve((size_t)4194304 * 2);
  float* Sc = (float*)carve((size_t)2097152 * 4);
  u16* Scb  = (u16*)carve((size_t)2097152 * 2);
  u16* Yb   = (u16*)carve((size_t)4194304 * 2);
  unsigned* ctr = (unsigned*)carve(128);
  (void)in_sizes; (void)n_in; (void)out_size; (void)ws_size;

  prep_kernel<<<2064, 256, 0, stream>>>(X, Xb, Wq, Wqb, Wk, Wkb, Wv, Wvb, Wc, Wcb, Ltri, Bmb);
  qkv_gemm<<<dim3(32, 24), 256, 0, stream>>>(Xb, Wqb, Wkb, Wvb, Qb, Kb, Vb, ctr);
  state_pf<<<640, 256, 0, stream>>>(Kb, Vb, VT, Sc, Scb, Wcb, Bmb, Wcpb, ctr);
  chunk_attn<<<dim3(32, 16), 256, 0, stream>>>(Qb, Kb, VT, Scb, Yb);
  out_gemm<<<dim3(32, 8), 256, 0, stream>>>(Yb, Wcpb, out);
}

// Round 14
// 139.813 us; speedup vs baseline: 1.0304x; 1.0304x over previous
//
#include <hip/hip_runtime.h>

// LinearAttentionSVAR: B=2, L=2048, D=1024, H=16, d=64.
// Round 14: revert r13's fence disaster. 5 launches, zero cross-block sync:
//  prep -> qkv -> state_fold (state 512 + Wc' fold 128, independent blocks)
//  -> chunk_attn (computes its own exclusive chunk-prefix from Sc in-block,
//  bit-identical fp32 sum + f2bf; Scb buffer and prefix launch deleted)
//  -> out. All other bodies round-10 verbatim.

#define DEV static __device__ __forceinline__

typedef unsigned short u16;
typedef unsigned long long u64;
typedef __attribute__((ext_vector_type(4))) float f32x4;
typedef __attribute__((ext_vector_type(8))) short bf16x8;

DEV u16 f2bf(float f){
  union { float f; unsigned u; } v; v.f = f;
  unsigned r = v.u + 0x7FFFu + ((v.u >> 16) & 1u);
  return (u16)(r >> 16);
}

DEV void store_val(float* p, float v){ *p = v; }
DEV void store_val(u16* p, float v){ *p = f2bf(v); }

DEV void gload16(const void* g, void* l){
  __builtin_amdgcn_global_load_lds((const __attribute__((address_space(1))) void*)g,
                                   (__attribute__((address_space(3))) void*)l, 16, 0, 0);
}

// ---------------- 1. prep: bf16 converts + per-head Bm ----------------
__global__ __launch_bounds__(256) void prep_kernel(
    const float* __restrict__ X, u16* __restrict__ Xb,
    const float* __restrict__ Wq, u16* __restrict__ Wqb,
    const float* __restrict__ Wk, u16* __restrict__ Wkb,
    const float* __restrict__ Wv, u16* __restrict__ Wvb,
    const float* __restrict__ Wc, u16* __restrict__ Wcb,
    const float* __restrict__ Ltri, u16* __restrict__ Bmb)
{
  const int bx = blockIdx.x, tid = threadIdx.x;
  if(bx < 16){
    __shared__ float Lm[64][65];
    int h = bx;
    const float* src = Ltri + (size_t)h * 4096;
    for(int i = tid; i < 4096; i += 256){
      int e = i >> 6, k = i & 63;
      Lm[e][k] = (k <= e) ? src[i] : 0.f;
    }
    __syncthreads();
    u16* out = Bmb + (size_t)h * 4096;
    for(int i = tid; i < 4096; i += 256){
      int e = i >> 6, dk = i & 63;
      float sum = 0.f;
      int kmax = e < dk ? e : dk;
      for(int k = 0; k <= kmax; k++) sum += Lm[e][k] * Lm[dk][k];
      out[i] = f2bf(sum);
    }
  } else {
    const int n0 = 4194304, n1 = 1048576, n2 = 1048576, n3 = 1048576, n4 = 1048576;
    int total = (n0 + n1 + n2 + n3 + n4) >> 2;
    for(int i = (bx - 16) * 256 + tid; i < total; i += 2048 * 256){
      int e = i << 2;
      const float* s; u16* d;
      if(e < n0){ s = X + e; d = Xb + e; }
      else if(e < n0 + n1){ s = Wq + (e - n0); d = Wqb + (e - n0); }
      else if(e < n0 + n1 + n2){ s = Wk + (e - n0 - n1); d = Wkb + (e - n0 - n1); }
      else if(e < n0 + n1 + n2 + n3){ s = Wv + (e - n0 - n1 - n2); d = Wvb + (e - n0 - n1 - n2); }
      else { s = Wc + (e - n0 - n1 - n2 - n3); d = Wcb + (e - n0 - n1 - n2 - n3); }
      float4 v = *(const float4*)s;
      u64 pk = (u64)f2bf(v.x) | ((u64)f2bf(v.y) << 16) | ((u64)f2bf(v.z) << 32) | ((u64)f2bf(v.w) << 48);
      *(u64*)d = pk;
    }
  }
}

// ---------------- GEMM tile body: BK=32, row-pair-fused swizzle, depth-2 ----------------
template<typename OutT>
DEV void gemm128_p2(const u16* __restrict__ A, const u16* __restrict__ W,
                    OutT* __restrict__ C, int bx, int by, int N, int K)
{
  __shared__ u16 L[3][8192];
  const int tid = threadIdx.x;
  const int wid = tid >> 6, lane = tid & 63;
  const int wr = wid >> 1, wc = wid & 1;
  const int lr = lane & 15, lq = lane >> 4;
  const u16* Ag = A + (size_t)(bx * 128) * K;
  const u16* Wg = W + (size_t)(by * 128) * K;

  const int p0 = tid >> 3, p1 = 32 + (tid >> 3);
  const int cl0 = (tid & 7) ^ (p0 & 7);
  const int cl1 = (tid & 7) ^ (p1 & 7);
  const int srow0 = 2 * p0 + (cl0 >> 2), skc0 = (cl0 & 3) * 8;
  const int srow1 = 2 * p1 + (cl1 >> 2), skc1 = (cl1 & 3) * 8;

  auto stagef = [&](int kt, int buf){
    gload16(Ag + (size_t)srow0 * K + kt * 32 + skc0, &L[buf][tid * 8]);
    gload16(Ag + (size_t)srow1 * K + kt * 32 + skc1, &L[buf][2048 + tid * 8]);
    gload16(Wg + (size_t)srow0 * K + kt * 32 + skc0, &L[buf][4096 + tid * 8]);
    gload16(Wg + (size_t)srow1 * K + kt * 32 + skc1, &L[buf][6144 + tid * 8]);
  };

  const int nt = K >> 5;
  f32x4 acc[4][4] = {};
  stagef(0, 0);
  stagef(1, 1);
  int cur = 0;
  for(int t = 0; t < nt; t++){
    if(t < nt - 1) asm volatile("s_waitcnt vmcnt(4)" ::: "memory");
    else           asm volatile("s_waitcnt vmcnt(0)" ::: "memory");
    __builtin_amdgcn_s_barrier();
    __builtin_amdgcn_sched_barrier(0);
    if(t + 2 < nt){
      int n2 = cur >= 1 ? cur - 1 : cur + 2;
      stagef(t + 2, n2);
    }
    const u16* Lb = L[cur];
    bf16x8 af[4], bfr[4];
#pragma unroll
    for(int i = 0; i < 4; i++){
      int row = wr * 64 + i * 16 + lr;
      int rh = row >> 1;
      int cph = (lq | ((row & 1) << 2)) ^ (rh & 7);
      af[i] = *(const bf16x8*)&Lb[rh * 64 + cph * 8];
    }
#pragma unroll
    for(int j = 0; j < 4; j++){
      int row = wc * 64 + j * 16 + lr;
      int rh = row >> 1;
      int cph = (lq | ((row & 1) << 2)) ^ (rh & 7);
      bfr[j] = *(const bf16x8*)&Lb[4096 + rh * 64 + cph * 8];
    }
#pragma unroll
    for(int i = 0; i < 4; i++)
#pragma unroll
      for(int j = 0; j < 4; j++)
        acc[i][j] = __builtin_amdgcn_mfma_f32_16x16x32_bf16(af[i], bfr[j], acc[i][j], 0, 0, 0);
    cur = cur == 2 ? 0 : cur + 1;
  }
#pragma unroll
  for(int i = 0; i < 4; i++)
#pragma unroll
    for(int j = 0; j < 4; j++)
#pragma unroll
      for(int r = 0; r < 4; r++){
        int row = bx * 128 + wr * 64 + i * 16 + lq * 4 + r;
        int col = by * 128 + wc * 64 + j * 16 + lr;
        store_val(C + (size_t)row * N + col, acc[i][j][r]);
      }
}

// ---------------- depth-3 variant (4 bufs) for 1-block/CU out_gemm ----------------
template<typename OutT>
DEV void gemm128_p3(const u16* __restrict__ A, const u16* __restrict__ W,
                    OutT* __restrict__ C, int bx, int by, int N, int K)
{
  __shared__ u16 L[4][8192];
  const int tid = threadIdx.x;
  const int wid = tid >> 6, lane = tid & 63;
  const int wr = wid >> 1, wc = wid & 1;
  const int lr = lane & 15, lq = lane >> 4;
  const u16* Ag = A + (size_t)(bx * 128) * K;
  const u16* Wg = W + (size_t)(by * 128) * K;

  const int p0 = tid >> 3, p1 = 32 + (tid >> 3);
  const int cl0 = (tid & 7) ^ (p0 & 7);
  const int cl1 = (tid & 7) ^ (p1 & 7);
  const int srow0 = 2 * p0 + (cl0 >> 2), skc0 = (cl0 & 3) * 8;
  const int srow1 = 2 * p1 + (cl1 >> 2), skc1 = (cl1 & 3) * 8;

  auto stagef = [&](int kt, int buf){
    gload16(Ag + (size_t)srow0 * K + kt * 32 + skc0, &L[buf][tid * 8]);
    gload16(Ag + (size_t)srow1 * K + kt * 32 + skc1, &L[buf][2048 + tid * 8]);
    gload16(Wg + (size_t)srow0 * K + kt * 32 + skc0, &L[buf][4096 + tid * 8]);
    gload16(Wg + (size_t)srow1 * K + kt * 32 + skc1, &L[buf][6144 + tid * 8]);
  };

  const int nt = K >> 5;
  f32x4 acc[4][4] = {};
  stagef(0, 0);
  stagef(1, 1);
  stagef(2, 2);
  for(int t = 0; t < nt; t++){
    if(t < nt - 2)       asm volatile("s_waitcnt vmcnt(8)" ::: "memory");
    else if(t == nt - 2) asm volatile("s_waitcnt vmcnt(4)" ::: "memory");
    else                 asm volatile("s_waitcnt vmcnt(0)" ::: "memory");
    __builtin_amdgcn_s_barrier();
    __builtin_amdgcn_sched_barrier(0);
    if(t + 3 < nt) stagef(t + 3, (t + 3) & 3);
    const u16* Lb = L[t & 3];
    bf16x8 af[4], bfr[4];
#pragma unroll
    for(int i = 0; i < 4; i++){
      int row = wr * 64 + i * 16 + lr;
      int rh = row >> 1;
      int cph = (lq | ((row & 1) << 2)) ^ (rh & 7);
      af[i] = *(const bf16x8*)&Lb[rh * 64 + cph * 8];
    }
#pragma unroll
    for(int j = 0; j < 4; j++){
      int row = wc * 64 + j * 16 + lr;
      int rh = row >> 1;
      int cph = (lq | ((row & 1) << 2)) ^ (rh & 7);
      bfr[j] = *(const bf16x8*)&Lb[4096 + rh * 64 + cph * 8];
    }
#pragma unroll
    for(int i = 0; i < 4; i++)
#pragma unroll
      for(int j = 0; j < 4; j++)
        acc[i][j] = __builtin_amdgcn_mfma_f32_16x16x32_bf16(af[i], bfr[j], acc[i][j], 0, 0, 0);
  }
#pragma unroll
  for(int i = 0; i < 4; i++)
#pragma unroll
    for(int j = 0; j < 4; j++)
#pragma unroll
      for(int r = 0; r < 4; r++){
        int row = bx * 128 + wr * 64 + i * 16 + lq * 4 + r;
        int col = by * 128 + wc * 64 + j * 16 + lr;
        store_val(C + (size_t)row * N + col, acc[i][j][r]);
      }
}

// ---------------- qkv: pure GEMM (768 blocks = 3.0/CU) ----------------
__global__ __launch_bounds__(256) void qkv_gemm(
    const u16* __restrict__ Xb,
    const u16* __restrict__ Wq, const u16* __restrict__ Wk, const u16* __restrict__ Wv,
    u16* __restrict__ Q, u16* __restrict__ Ko, u16* __restrict__ V)
{
  int sel = blockIdx.y >> 3, byl = blockIdx.y & 7;
  const u16* W = sel == 0 ? Wq : sel == 1 ? Wk : Wv;
  u16* C = sel == 0 ? Q : sel == 1 ? Ko : V;
  gemm128_p2<u16>(Xb, W, C, blockIdx.x, byl, 1024, 1024);
}

__global__ __launch_bounds__(256) void out_gemm(
    const u16* __restrict__ Yb, const u16* __restrict__ Wcpb, float* __restrict__ out)
{
  gemm128_p3<float>(Yb, Wcpb, out, blockIdx.x, blockIdx.y, 1024, 1024);
}

// ---------------- state_fold: state (512) + Wc' fold (128), all independent ----------------
__global__ __launch_bounds__(256) void state_fold(
    const u16* __restrict__ Kb, const u16* __restrict__ Vb,
    u16* __restrict__ VT, float* __restrict__ Sc,
    const u16* __restrict__ Wcb, const u16* __restrict__ Bmb, u16* __restrict__ Wcpb)
{
  const int bxg = blockIdx.x, tid = threadIdx.x;
  if(bxg >= 512){
    int ob = bxg - 512;
    int rt = ob & 7, h = ob >> 3;
    int wid = tid >> 6, lane = tid & 63;
    int lr = lane & 15, lk8 = (lane >> 4) * 8, lq = lane >> 4;
    const u16* ab  = Wcb + (size_t)(rt * 128) * 1024 + h * 64;
    const u16* bm  = Bmb + (size_t)h * 4096;
    f32x4 acc[2][4] = {};
#pragma unroll
    for(int i = 0; i < 2; i++){
      int mf = wid * 2 + i;
#pragma unroll
      for(int ks = 0; ks < 2; ks++){
        bf16x8 a = *(const bf16x8*)(ab + (size_t)(mf * 16 + lr) * 1024 + ks * 32 + lk8);
#pragma unroll
        for(int nf = 0; nf < 4; nf++){
          bf16x8 bfr = *(const bf16x8*)(bm + (nf * 16 + lr) * 64 + ks * 32 + lk8);
          acc[i][nf] = __builtin_amdgcn_mfma_f32_16x16x32_bf16(a, bfr, acc[i][nf], 0, 0, 0);
        }
      }
    }
#pragma unroll
    for(int i = 0; i < 2; i++)
#pragma unroll
      for(int nf = 0; nf < 4; nf++)
#pragma unroll
        for(int r = 0; r < 4; r++){
          int row = rt * 128 + (wid * 2 + i) * 16 + lq * 4 + r;
          int col = h * 64 + nf * 16 + lr;
          Wcpb[(size_t)row * 1024 + col] = f2bf(acc[i][nf][r]);
        }
    return;
  }

  int bh = bxg >> 4, c = bxg & 15;
  int b = bh >> 4, h = bh & 15;
  __shared__ u16 Kt[128][72];
  __shared__ u16 Vt[128][72];
  __shared__ u16 KtT[64][136];
  __shared__ u16 VtT[64][136];
  int rr = tid >> 3;
  int cc = (tid & 7) * 8;
  const u16* kg = Kb + (size_t)(b * 2048 + c * 128) * 1024 + h * 64;
  const u16* vg = Vb + (size_t)(b * 2048 + c * 128) * 1024 + h * 64;
#pragma unroll
  for(int p = 0; p < 4; p++){
    int row = rr + p * 32;
    *(int4*)&Kt[row][cc] = *(const int4*)(kg + (size_t)row * 1024 + cc);
    *(int4*)&Vt[row][cc] = *(const int4*)(vg + (size_t)row * 1024 + cc);
  }
  __syncthreads();
  int d = tid >> 2, tseg = (tid & 3) * 32;
#pragma unroll
  for(int j = 0; j < 32; j += 8){
    u16 tk[8] __attribute__((aligned(16)));
    u16 tv[8] __attribute__((aligned(16)));
#pragma unroll
    for(int q = 0; q < 8; q++){
      tk[q] = Kt[tseg + j + q][d];
      tv[q] = Vt[tseg + j + q][d];
    }
    *(int4*)&KtT[d][tseg + j] = *(const int4*)tk;
    *(int4*)&VtT[d][tseg + j] = *(const int4*)tv;
  }
  __syncthreads();
  {
    u16* vto = VT + (size_t)bh * 64 * 2048 + (size_t)d * 2048 + c * 128 + tseg;
#pragma unroll
    for(int j = 0; j < 32; j += 8)
      *(int4*)(vto + j) = *(const int4*)&VtT[d][tseg + j];
  }
  int wid = tid >> 6, lane = tid & 63;
  int wr = wid >> 1, wc = wid & 1;
  int lr = lane & 15, lk8 = (lane >> 4) * 8, lq = lane >> 4;
  f32x4 acc[2][2] = {};
#pragma unroll
  for(int ks = 0; ks < 4; ks++){
    bf16x8 a[2], bb[2];
#pragma unroll
    for(int i = 0; i < 2; i++) a[i]  = *(const bf16x8*)&VtT[wr * 32 + i * 16 + lr][ks * 32 + lk8];
#pragma unroll
    for(int j = 0; j < 2; j++) bb[j] = *(const bf16x8*)&KtT[wc * 32 + j * 16 + lr][ks * 32 + lk8];
#pragma unroll
    for(int i = 0; i < 2; i++)
#pragma unroll
      for(int j = 0; j < 2; j++)
        acc[i][j] = __builtin_amdgcn_mfma_f32_16x16x32_bf16(a[i], bb[j], acc[i][j], 0, 0, 0);
  }
  float* outp = Sc + ((size_t)bh * 16 + c) * 4096;
#pragma unroll
  for(int i = 0; i < 2; i++)
#pragma unroll
    for(int j = 0; j < 2; j++)
#pragma unroll
      for(int r = 0; r < 4; r++){
        int e = wr * 32 + i * 16 + lq * 4 + r, dk = wc * 32 + j * 16 + lr;
        outp[e * 64 + dk] = acc[i][j][r];
      }
}

// ---------------- chunk_attn: computes its own exclusive prefix from Sc ----------------
__global__ __launch_bounds__(256) void chunk_attn(
    const u16* __restrict__ Q, const u16* __restrict__ Kmat,
    const u16* __restrict__ VT, const float* __restrict__ Sc, u16* __restrict__ Y)
{
  int bh = blockIdx.x, c = blockIdx.y;
  int b = bh >> 4, h = bh & 15;
  int t = threadIdx.x, wid = t >> 6, lane = t & 63;
  int lr = lane & 15, lk8 = (lane >> 4) * 8, lq = lane >> 4;
  __shared__ u16 S[128 * 128];
  const u16* qg = Q    + (size_t)(b * 2048 + c * 128) * 1024 + h * 64;
  const u16* kg = Kmat + (size_t)(b * 2048 + c * 128) * 1024 + h * 64;
  const float* scf = Sc + (size_t)bh * 65536;
  const u16* vt  = VT + (size_t)bh * 64 * 2048 + (size_t)c * 128;
  u16* yg = Y + (size_t)(b * 2048 + c * 128) * 1024 + h * 64;

  // on-the-fly exclusive prefix fragments (bit-identical to old Scb path:
  // fp32 sum in t-ascending order, then one f2bf)
  bf16x8 scfrag[4][2];
#pragma unroll
  for(int nf = 0; nf < 4; nf++)
#pragma unroll
    for(int ks = 0; ks < 2; ks++){
      f32x4 s0 = {}, s1 = {};
      const float* p0 = scf + (nf * 16 + lr) * 64 + ks * 32 + lk8;
      for(int tc = 0; tc < c; tc++){
        s0 += *(const f32x4*)(p0 + (size_t)tc * 4096);
        s1 += *(const f32x4*)(p0 + (size_t)tc * 4096 + 4);
      }
      u16 hh[8] __attribute__((aligned(16)));
#pragma unroll
      for(int q = 0; q < 4; q++){ hh[q] = f2bf(s0[q]); hh[4 + q] = f2bf(s1[q]); }
      scfrag[nf][ks] = *(const bf16x8*)hh;
    }

  bf16x8 a[2][2];
#pragma unroll
  for(int mi = 0; mi < 2; mi++){
    int mf = wid + mi * 4;
    int Rm = mf * 16;
    if((mf & 1) == 0){
      int zr = Rm + (lane >> 2), zc = Rm + 16 + (lane & 3) * 4;
      int zoff = ((zr * 128 + zc) * 2) ^ ((zr & 7) << 4);
      *(u64*)((char*)S + zoff) = 0ULL;
    }
#pragma unroll
    for(int ks = 0; ks < 2; ks++) a[mi][ks] = *(const bf16x8*)(qg + (size_t)(Rm + lr) * 1024 + ks * 32 + lk8);
    for(int nf = 0; nf <= mf; nf++){
      f32x4 acc = {};
#pragma unroll
      for(int ks = 0; ks < 2; ks++){
        bf16x8 bb = *(const bf16x8*)(kg + (size_t)(nf * 16 + lr) * 1024 + ks * 32 + lk8);
        acc = __builtin_amdgcn_mfma_f32_16x16x32_bf16(a[mi][ks], bb, acc, 0, 0, 0);
      }
#pragma unroll
      for(int r = 0; r < 4; r++){
        int row = lq * 4 + r, col = lr;
        float v = acc[r];
        if(nf == mf && col > row) v = 0.f;
        int grow = Rm + row, gcol = nf * 16 + col;
        int off = ((grow * 128 + gcol) * 2) ^ ((grow & 7) << 4);
        *(u16*)((char*)S + off) = f2bf(v);
      }
    }
  }
  f32x4 acc2[2][4] = {};
#pragma unroll
  for(int nf = 0; nf < 4; nf++)
#pragma unroll
    for(int ks = 0; ks < 2; ks++){
      bf16x8 bb = scfrag[nf][ks];
#pragma unroll
      for(int mi = 0; mi < 2; mi++)
        acc2[mi][nf] = __builtin_amdgcn_mfma_f32_16x16x32_bf16(a[mi][ks], bb, acc2[mi][nf], 0, 0, 0);
    }
  int ks0 = wid >> 1;
  int row0 = wid * 16 + lr;
  int row1 = (wid + 4) * 16 + lr;
  for(int ks = 0; ks <= ks0 + 2; ks++){
    bf16x8 bb[4];
#pragma unroll
    for(int nf = 0; nf < 4; nf++)
      bb[nf] = *(const bf16x8*)(vt + (size_t)(nf * 16 + lr) * 2048 + ks * 32 + lk8);
    if(ks <= ks0){
      int off = ((row0 * 128 + ks * 32 + lk8) * 2) ^ ((row0 & 7) << 4);
      bf16x8 af = *(const bf16x8*)((char*)S + off);
#pragma unroll
      for(int nf = 0; nf < 4; nf++)
        acc2[0][nf] = __builtin_amdgcn_mfma_f32_16x16x32_bf16(af, bb[nf], acc2[0][nf], 0, 0, 0);
    }
    {
      int off = ((row1 * 128 + ks * 32 + lk8) * 2) ^ ((row1 & 7) << 4);
      bf16x8 af = *(const bf16x8*)((char*)S + off);
#pragma unroll
      for(int nf = 0; nf < 4; nf++)
        acc2[1][nf] = __builtin_amdgcn_mfma_f32_16x16x32_bf16(af, bb[nf], acc2[1][nf], 0, 0, 0);
    }
  }
#pragma unroll
  for(int mi = 0; mi < 2; mi++){
    int Rm = (wid + mi * 4) * 16;
#pragma unroll
    for(int nf = 0; nf < 4; nf++)
#pragma unroll
      for(int r = 0; r < 4; r++){
        int grow = Rm + lq * 4 + r, gcol = nf * 16 + lr;
        yg[(size_t)grow * 1024 + gcol] = f2bf(acc2[mi][nf][r]);
      }
  }
}

// ---------------- launch ----------------
extern "C" void kernel_launch(void* const* d_in, const int* in_sizes, int n_in,
                              void* d_out, int out_size, void* d_ws, size_t ws_size,
                              hipStream_t stream)
{
  const float* X    = (const float*)d_in[0];
  const float* Wq   = (const float*)d_in[1];
  const float* Wk   = (const float*)d_in[2];
  const float* Wv   = (const float*)d_in[3];
  const float* Wc   = (const float*)d_in[4];
  const float* Ltri = (const float*)d_in[5];
  float* out = (float*)d_out;

  char* ws = (char*)d_ws;
  size_t off = 0;
  auto carve = [&](size_t bytes) -> char* {
    char* p = ws + off;
    off += (bytes + 255) & ~(size_t)255;
    return p;
  };
  u16* Xb   = (u16*)carve((size_t)4194304 * 2);
  u16* Wqb  = (u16*)carve((size_t)1048576 * 2);
  u16* Wkb  = (u16*)carve((size_t)1048576 * 2);
  u16* Wvb  = (u16*)carve((size_t)1048576 * 2);
  u16* Wcb  = (u16*)carve((size_t)1048576 * 2);
  u16* Wcpb = (u16*)carve((size_t)1048576 * 2);
  u16* Bmb  = (u16*)carve((size_t)65536 * 2);
  u16* Qb   = (u16*)carve((size_t)4194304 * 2);
  u16* Kb   = (u16*)carve((size_t)4194304 * 2);
  u16* Vb   = (u16*)carve((size_t)4194304 * 2);
  u16* VT   = (u16*)carve((size_t)4194304 * 2);
  float* Sc = (float*)carve((size_t)2097152 * 4);
  u16* Yb   = (u16*)carve((size_t)4194304 * 2);
  (void)in_sizes; (void)n_in; (void)out_size; (void)ws_size;

  prep_kernel<<<2064, 256, 0, stream>>>(X, Xb, Wq, Wqb, Wk, Wkb, Wv, Wvb, Wc, Wcb, Ltri, Bmb);
  qkv_gemm<<<dim3(32, 24), 256, 0, stream>>>(Xb, Wqb, Wkb, Wvb, Qb, Kb, Vb);
  state_fold<<<640, 256, 0, stream>>>(Kb, Vb, VT, Sc, Wcb, Bmb, Wcpb);
  chunk_attn<<<dim3(32, 16), 256, 0, stream>>>(Qb, Kb, VT, Sc, Yb);
  out_gemm<<<dim3(32, 8), 256, 0, stream>>>(Yb, Wcpb, out);
}

// Round 15
// 105.770 us; speedup vs baseline: 1.3621x; 1.3219x over previous
//
#include <hip/hip_runtime.h>

// LinearAttentionSVAR: B=2, L=2048, D=1024, H=16, d=64.
// Round 15: r14's prefix-in-attn idea, fixed. Each attn block computes the
// exclusive chunk-prefix ONCE, block-cooperatively and coalesced (float4 lane
// = tid+p*256), into an 8KB bf16 LDS buffer Sp; fragments read Sp. Bit-identical
// fp32 sum order + f2bf vs the old prefix_state/Scb path. 5 launches, no
// cross-block sync. All other bodies round-10 verbatim.

#define DEV static __device__ __forceinline__

typedef unsigned short u16;
typedef unsigned long long u64;
typedef __attribute__((ext_vector_type(4))) float f32x4;
typedef __attribute__((ext_vector_type(8))) short bf16x8;

DEV u16 f2bf(float f){
  union { float f; unsigned u; } v; v.f = f;
  unsigned r = v.u + 0x7FFFu + ((v.u >> 16) & 1u);
  return (u16)(r >> 16);
}

DEV void store_val(float* p, float v){ *p = v; }
DEV void store_val(u16* p, float v){ *p = f2bf(v); }

DEV void gload16(const void* g, void* l){
  __builtin_amdgcn_global_load_lds((const __attribute__((address_space(1))) void*)g,
                                   (__attribute__((address_space(3))) void*)l, 16, 0, 0);
}

// ---------------- 1. prep: bf16 converts + per-head Bm ----------------
__global__ __launch_bounds__(256) void prep_kernel(
    const float* __restrict__ X, u16* __restrict__ Xb,
    const float* __restrict__ Wq, u16* __restrict__ Wqb,
    const float* __restrict__ Wk, u16* __restrict__ Wkb,
    const float* __restrict__ Wv, u16* __restrict__ Wvb,
    const float* __restrict__ Wc, u16* __restrict__ Wcb,
    const float* __restrict__ Ltri, u16* __restrict__ Bmb)
{
  const int bx = blockIdx.x, tid = threadIdx.x;
  if(bx < 16){
    __shared__ float Lm[64][65];
    int h = bx;
    const float* src = Ltri + (size_t)h * 4096;
    for(int i = tid; i < 4096; i += 256){
      int e = i >> 6, k = i & 63;
      Lm[e][k] = (k <= e) ? src[i] : 0.f;
    }
    __syncthreads();
    u16* out = Bmb + (size_t)h * 4096;
    for(int i = tid; i < 4096; i += 256){
      int e = i >> 6, dk = i & 63;
      float sum = 0.f;
      int kmax = e < dk ? e : dk;
      for(int k = 0; k <= kmax; k++) sum += Lm[e][k] * Lm[dk][k];
      out[i] = f2bf(sum);
    }
  } else {
    const int n0 = 4194304, n1 = 1048576, n2 = 1048576, n3 = 1048576, n4 = 1048576;
    int total = (n0 + n1 + n2 + n3 + n4) >> 2;
    for(int i = (bx - 16) * 256 + tid; i < total; i += 2048 * 256){
      int e = i << 2;
      const float* s; u16* d;
      if(e < n0){ s = X + e; d = Xb + e; }
      else if(e < n0 + n1){ s = Wq + (e - n0); d = Wqb + (e - n0); }
      else if(e < n0 + n1 + n2){ s = Wk + (e - n0 - n1); d = Wkb + (e - n0 - n1); }
      else if(e < n0 + n1 + n2 + n3){ s = Wv + (e - n0 - n1 - n2); d = Wvb + (e - n0 - n1 - n2); }
      else { s = Wc + (e - n0 - n1 - n2 - n3); d = Wcb + (e - n0 - n1 - n2 - n3); }
      float4 v = *(const float4*)s;
      u64 pk = (u64)f2bf(v.x) | ((u64)f2bf(v.y) << 16) | ((u64)f2bf(v.z) << 32) | ((u64)f2bf(v.w) << 48);
      *(u64*)d = pk;
    }
  }
}

// ---------------- GEMM tile body: BK=32, row-pair-fused swizzle, depth-2 ----------------
template<typename OutT>
DEV void gemm128_p2(const u16* __restrict__ A, const u16* __restrict__ W,
                    OutT* __restrict__ C, int bx, int by, int N, int K)
{
  __shared__ u16 L[3][8192];
  const int tid = threadIdx.x;
  const int wid = tid >> 6, lane = tid & 63;
  const int wr = wid >> 1, wc = wid & 1;
  const int lr = lane & 15, lq = lane >> 4;
  const u16* Ag = A + (size_t)(bx * 128) * K;
  const u16* Wg = W + (size_t)(by * 128) * K;

  const int p0 = tid >> 3, p1 = 32 + (tid >> 3);
  const int cl0 = (tid & 7) ^ (p0 & 7);
  const int cl1 = (tid & 7) ^ (p1 & 7);
  const int srow0 = 2 * p0 + (cl0 >> 2), skc0 = (cl0 & 3) * 8;
  const int srow1 = 2 * p1 + (cl1 >> 2), skc1 = (cl1 & 3) * 8;

  auto stagef = [&](int kt, int buf){
    gload16(Ag + (size_t)srow0 * K + kt * 32 + skc0, &L[buf][tid * 8]);
    gload16(Ag + (size_t)srow1 * K + kt * 32 + skc1, &L[buf][2048 + tid * 8]);
    gload16(Wg + (size_t)srow0 * K + kt * 32 + skc0, &L[buf][4096 + tid * 8]);
    gload16(Wg + (size_t)srow1 * K + kt * 32 + skc1, &L[buf][6144 + tid * 8]);
  };

  const int nt = K >> 5;
  f32x4 acc[4][4] = {};
  stagef(0, 0);
  stagef(1, 1);
  int cur = 0;
  for(int t = 0; t < nt; t++){
    if(t < nt - 1) asm volatile("s_waitcnt vmcnt(4)" ::: "memory");
    else           asm volatile("s_waitcnt vmcnt(0)" ::: "memory");
    __builtin_amdgcn_s_barrier();
    __builtin_amdgcn_sched_barrier(0);
    if(t + 2 < nt){
      int n2 = cur >= 1 ? cur - 1 : cur + 2;
      stagef(t + 2, n2);
    }
    const u16* Lb = L[cur];
    bf16x8 af[4], bfr[4];
#pragma unroll
    for(int i = 0; i < 4; i++){
      int row = wr * 64 + i * 16 + lr;
      int rh = row >> 1;
      int cph = (lq | ((row & 1) << 2)) ^ (rh & 7);
      af[i] = *(const bf16x8*)&Lb[rh * 64 + cph * 8];
    }
#pragma unroll
    for(int j = 0; j < 4; j++){
      int row = wc * 64 + j * 16 + lr;
      int rh = row >> 1;
      int cph = (lq | ((row & 1) << 2)) ^ (rh & 7);
      bfr[j] = *(const bf16x8*)&Lb[4096 + rh * 64 + cph * 8];
    }
#pragma unroll
    for(int i = 0; i < 4; i++)
#pragma unroll
      for(int j = 0; j < 4; j++)
        acc[i][j] = __builtin_amdgcn_mfma_f32_16x16x32_bf16(af[i], bfr[j], acc[i][j], 0, 0, 0);
    cur = cur == 2 ? 0 : cur + 1;
  }
#pragma unroll
  for(int i = 0; i < 4; i++)
#pragma unroll
    for(int j = 0; j < 4; j++)
#pragma unroll
      for(int r = 0; r < 4; r++){
        int row = bx * 128 + wr * 64 + i * 16 + lq * 4 + r;
        int col = by * 128 + wc * 64 + j * 16 + lr;
        store_val(C + (size_t)row * N + col, acc[i][j][r]);
      }
}

// ---------------- depth-3 variant (4 bufs) for 1-block/CU out_gemm ----------------
template<typename OutT>
DEV void gemm128_p3(const u16* __restrict__ A, const u16* __restrict__ W,
                    OutT* __restrict__ C, int bx, int by, int N, int K)
{
  __shared__ u16 L[4][8192];
  const int tid = threadIdx.x;
  const int wid = tid >> 6, lane = tid & 63;
  const int wr = wid >> 1, wc = wid & 1;
  const int lr = lane & 15, lq = lane >> 4;
  const u16* Ag = A + (size_t)(bx * 128) * K;
  const u16* Wg = W + (size_t)(by * 128) * K;

  const int p0 = tid >> 3, p1 = 32 + (tid >> 3);
  const int cl0 = (tid & 7) ^ (p0 & 7);
  const int cl1 = (tid & 7) ^ (p1 & 7);
  const int srow0 = 2 * p0 + (cl0 >> 2), skc0 = (cl0 & 3) * 8;
  const int srow1 = 2 * p1 + (cl1 >> 2), skc1 = (cl1 & 3) * 8;

  auto stagef = [&](int kt, int buf){
    gload16(Ag + (size_t)srow0 * K + kt * 32 + skc0, &L[buf][tid * 8]);
    gload16(Ag + (size_t)srow1 * K + kt * 32 + skc1, &L[buf][2048 + tid * 8]);
    gload16(Wg + (size_t)srow0 * K + kt * 32 + skc0, &L[buf][4096 + tid * 8]);
    gload16(Wg + (size_t)srow1 * K + kt * 32 + skc1, &L[buf][6144 + tid * 8]);
  };

  const int nt = K >> 5;
  f32x4 acc[4][4] = {};
  stagef(0, 0);
  stagef(1, 1);
  stagef(2, 2);
  for(int t = 0; t < nt; t++){
    if(t < nt - 2)       asm volatile("s_waitcnt vmcnt(8)" ::: "memory");
    else if(t == nt - 2) asm volatile("s_waitcnt vmcnt(4)" ::: "memory");
    else                 asm volatile("s_waitcnt vmcnt(0)" ::: "memory");
    __builtin_amdgcn_s_barrier();
    __builtin_amdgcn_sched_barrier(0);
    if(t + 3 < nt) stagef(t + 3, (t + 3) & 3);
    const u16* Lb = L[t & 3];
    bf16x8 af[4], bfr[4];
#pragma unroll
    for(int i = 0; i < 4; i++){
      int row = wr * 64 + i * 16 + lr;
      int rh = row >> 1;
      int cph = (lq | ((row & 1) << 2)) ^ (rh & 7);
      af[i] = *(const bf16x8*)&Lb[rh * 64 + cph * 8];
    }
#pragma unroll
    for(int j = 0; j < 4; j++){
      int row = wc * 64 + j * 16 + lr;
      int rh = row >> 1;
      int cph = (lq | ((row & 1) << 2)) ^ (rh & 7);
      bfr[j] = *(const bf16x8*)&Lb[4096 + rh * 64 + cph * 8];
    }
#pragma unroll
    for(int i = 0; i < 4; i++)
#pragma unroll
      for(int j = 0; j < 4; j++)
        acc[i][j] = __builtin_amdgcn_mfma_f32_16x16x32_bf16(af[i], bfr[j], acc[i][j], 0, 0, 0);
  }
#pragma unroll
  for(int i = 0; i < 4; i++)
#pragma unroll
    for(int j = 0; j < 4; j++)
#pragma unroll
      for(int r = 0; r < 4; r++){
        int row = bx * 128 + wr * 64 + i * 16 + lq * 4 + r;
        int col = by * 128 + wc * 64 + j * 16 + lr;
        store_val(C + (size_t)row * N + col, acc[i][j][r]);
      }
}

// ---------------- qkv: pure GEMM (768 blocks = 3.0/CU) ----------------
__global__ __launch_bounds__(256) void qkv_gemm(
    const u16* __restrict__ Xb,
    const u16* __restrict__ Wq, const u16* __restrict__ Wk, const u16* __restrict__ Wv,
    u16* __restrict__ Q, u16* __restrict__ Ko, u16* __restrict__ V)
{
  int sel = blockIdx.y >> 3, byl = blockIdx.y & 7;
  const u16* W = sel == 0 ? Wq : sel == 1 ? Wk : Wv;
  u16* C = sel == 0 ? Q : sel == 1 ? Ko : V;
  gemm128_p2<u16>(Xb, W, C, blockIdx.x, byl, 1024, 1024);
}

__global__ __launch_bounds__(256) void out_gemm(
    const u16* __restrict__ Yb, const u16* __restrict__ Wcpb, float* __restrict__ out)
{
  gemm128_p3<float>(Yb, Wcpb, out, blockIdx.x, blockIdx.y, 1024, 1024);
}

// ---------------- state_fold: state (512) + Wc' fold (128), all independent ----------------
__global__ __launch_bounds__(256) void state_fold(
    const u16* __restrict__ Kb, const u16* __restrict__ Vb,
    u16* __restrict__ VT, float* __restrict__ Sc,
    const u16* __restrict__ Wcb, const u16* __restrict__ Bmb, u16* __restrict__ Wcpb)
{
  const int bxg = blockIdx.x, tid = threadIdx.x;
  if(bxg >= 512){
    int ob = bxg - 512;
    int rt = ob & 7, h = ob >> 3;
    int wid = tid >> 6, lane = tid & 63;
    int lr = lane & 15, lk8 = (lane >> 4) * 8, lq = lane >> 4;
    const u16* ab  = Wcb + (size_t)(rt * 128) * 1024 + h * 64;
    const u16* bm  = Bmb + (size_t)h * 4096;
    f32x4 acc[2][4] = {};
#pragma unroll
    for(int i = 0; i < 2; i++){
      int mf = wid * 2 + i;
#pragma unroll
      for(int ks = 0; ks < 2; ks++){
        bf16x8 a = *(const bf16x8*)(ab + (size_t)(mf * 16 + lr) * 1024 + ks * 32 + lk8);
#pragma unroll
        for(int nf = 0; nf < 4; nf++){
          bf16x8 bfr = *(const bf16x8*)(bm + (nf * 16 + lr) * 64 + ks * 32 + lk8);
          acc[i][nf] = __builtin_amdgcn_mfma_f32_16x16x32_bf16(a, bfr, acc[i][nf], 0, 0, 0);
        }
      }
    }
#pragma unroll
    for(int i = 0; i < 2; i++)
#pragma unroll
      for(int nf = 0; nf < 4; nf++)
#pragma unroll
        for(int r = 0; r < 4; r++){
          int row = rt * 128 + (wid * 2 + i) * 16 + lq * 4 + r;
          int col = h * 64 + nf * 16 + lr;
          Wcpb[(size_t)row * 1024 + col] = f2bf(acc[i][nf][r]);
        }
    return;
  }

  int bh = bxg >> 4, c = bxg & 15;
  int b = bh >> 4, h = bh & 15;
  __shared__ u16 Kt[128][72];
  __shared__ u16 Vt[128][72];
  __shared__ u16 KtT[64][136];
  __shared__ u16 VtT[64][136];
  int rr = tid >> 3;
  int cc = (tid & 7) * 8;
  const u16* kg = Kb + (size_t)(b * 2048 + c * 128) * 1024 + h * 64;
  const u16* vg = Vb + (size_t)(b * 2048 + c * 128) * 1024 + h * 64;
#pragma unroll
  for(int p = 0; p < 4; p++){
    int row = rr + p * 32;
    *(int4*)&Kt[row][cc] = *(const int4*)(kg + (size_t)row * 1024 + cc);
    *(int4*)&Vt[row][cc] = *(const int4*)(vg + (size_t)row * 1024 + cc);
  }
  __syncthreads();
  int d = tid >> 2, tseg = (tid & 3) * 32;
#pragma unroll
  for(int j = 0; j < 32; j += 8){
    u16 tk[8] __attribute__((aligned(16)));
    u16 tv[8] __attribute__((aligned(16)));
#pragma unroll
    for(int q = 0; q < 8; q++){
      tk[q] = Kt[tseg + j + q][d];
      tv[q] = Vt[tseg + j + q][d];
    }
    *(int4*)&KtT[d][tseg + j] = *(const int4*)tk;
    *(int4*)&VtT[d][tseg + j] = *(const int4*)tv;
  }
  __syncthreads();
  {
    u16* vto = VT + (size_t)bh * 64 * 2048 + (size_t)d * 2048 + c * 128 + tseg;
#pragma unroll
    for(int j = 0; j < 32; j += 8)
      *(int4*)(vto + j) = *(const int4*)&VtT[d][tseg + j];
  }
  int wid = tid >> 6, lane = tid & 63;
  int wr = wid >> 1, wc = wid & 1;
  int lr = lane & 15, lk8 = (lane >> 4) * 8, lq = lane >> 4;
  f32x4 acc[2][2] = {};
#pragma unroll
  for(int ks = 0; ks < 4; ks++){
    bf16x8 a[2], bb[2];
#pragma unroll
    for(int i = 0; i < 2; i++) a[i]  = *(const bf16x8*)&VtT[wr * 32 + i * 16 + lr][ks * 32 + lk8];
#pragma unroll
    for(int j = 0; j < 2; j++) bb[j] = *(const bf16x8*)&KtT[wc * 32 + j * 16 + lr][ks * 32 + lk8];
#pragma unroll
    for(int i = 0; i < 2; i++)
#pragma unroll
      for(int j = 0; j < 2; j++)
        acc[i][j] = __builtin_amdgcn_mfma_f32_16x16x32_bf16(a[i], bb[j], acc[i][j], 0, 0, 0);
  }
  float* outp = Sc + ((size_t)bh * 16 + c) * 4096;
#pragma unroll
  for(int i = 0; i < 2; i++)
#pragma unroll
    for(int j = 0; j < 2; j++)
#pragma unroll
      for(int r = 0; r < 4; r++){
        int e = wr * 32 + i * 16 + lq * 4 + r, dk = wc * 32 + j * 16 + lr;
        outp[e * 64 + dk] = acc[i][j][r];
      }
}

// ---------------- chunk_attn: block-cooperative prefix in LDS ----------------
__global__ __launch_bounds__(256) void chunk_attn(
    const u16* __restrict__ Q, const u16* __restrict__ Kmat,
    const u16* __restrict__ VT, const float* __restrict__ Sc, u16* __restrict__ Y)
{
  int bh = blockIdx.x, c = blockIdx.y;
  int b = bh >> 4, h = bh & 15;
  int t = threadIdx.x, wid = t >> 6, lane = t & 63;
  int lr = lane & 15, lk8 = (lane >> 4) * 8, lq = lane >> 4;
  __shared__ u16 S[128 * 128];   // score buffer (XOR-swizzled, wave-private rows)
  __shared__ u16 Sp[4096];       // bf16 exclusive prefix state [64 e][64 dk]
  const u16* qg = Q    + (size_t)(b * 2048 + c * 128) * 1024 + h * 64;
  const u16* kg = Kmat + (size_t)(b * 2048 + c * 128) * 1024 + h * 64;
  const float* scf = Sc + (size_t)bh * 65536;
  const u16* vt  = VT + (size_t)bh * 64 * 2048 + (size_t)c * 128;
  u16* yg = Y + (size_t)(b * 2048 + c * 128) * 1024 + h * 64;

  // block-cooperative exclusive prefix (coalesced; fp32 tc-ascending + f2bf,
  // bit-identical to the old prefix_state/Scb path)
  {
    f32x4 run[4] = {};
    for(int tc = 0; tc < c; tc++){
      const f32x4* sp = (const f32x4*)(scf + (size_t)tc * 4096);
#pragma unroll
      for(int p = 0; p < 4; p++) run[p] += sp[p * 256 + t];
    }
#pragma unroll
    for(int p = 0; p < 4; p++){
      u64 pk = (u64)f2bf(run[p][0]) | ((u64)f2bf(run[p][1]) << 16)
             | ((u64)f2bf(run[p][2]) << 32) | ((u64)f2bf(run[p][3]) << 48);
      *(u64*)&Sp[(p * 256 + t) * 4] = pk;
    }
  }
  __syncthreads();
  bf16x8 scfrag[4][2];
#pragma unroll
  for(int nf = 0; nf < 4; nf++)
#pragma unroll
    for(int ks = 0; ks < 2; ks++)
      scfrag[nf][ks] = *(const bf16x8*)&Sp[(nf * 16 + lr) * 64 + ks * 32 + lk8];

  bf16x8 a[2][2];
#pragma unroll
  for(int mi = 0; mi < 2; mi++){
    int mf = wid + mi * 4;
    int Rm = mf * 16;
    if((mf & 1) == 0){
      int zr = Rm + (lane >> 2), zc = Rm + 16 + (lane & 3) * 4;
      int zoff = ((zr * 128 + zc) * 2) ^ ((zr & 7) << 4);
      *(u64*)((char*)S + zoff) = 0ULL;
    }
#pragma unroll
    for(int ks = 0; ks < 2; ks++) a[mi][ks] = *(const bf16x8*)(qg + (size_t)(Rm + lr) * 1024 + ks * 32 + lk8);
    for(int nf = 0; nf <= mf; nf++){
      f32x4 acc = {};
#pragma unroll
      for(int ks = 0; ks < 2; ks++){
        bf16x8 bb = *(const bf16x8*)(kg + (size_t)(nf * 16 + lr) * 1024 + ks * 32 + lk8);
        acc = __builtin_amdgcn_mfma_f32_16x16x32_bf16(a[mi][ks], bb, acc, 0, 0, 0);
      }
#pragma unroll
      for(int r = 0; r < 4; r++){
        int row = lq * 4 + r, col = lr;
        float v = acc[r];
        if(nf == mf && col > row) v = 0.f;
        int grow = Rm + row, gcol = nf * 16 + col;
        int off = ((grow * 128 + gcol) * 2) ^ ((grow & 7) << 4);
        *(u16*)((char*)S + off) = f2bf(v);
      }
    }
  }
  f32x4 acc2[2][4] = {};
#pragma unroll
  for(int nf = 0; nf < 4; nf++)
#pragma unroll
    for(int ks = 0; ks < 2; ks++){
      bf16x8 bb = scfrag[nf][ks];
#pragma unroll
      for(int mi = 0; mi < 2; mi++)
        acc2[mi][nf] = __builtin_amdgcn_mfma_f32_16x16x32_bf16(a[mi][ks], bb, acc2[mi][nf], 0, 0, 0);
    }
  int ks0 = wid >> 1;
  int row0 = wid * 16 + lr;
  int row1 = (wid + 4) * 16 + lr;
  for(int ks = 0; ks <= ks0 + 2; ks++){
    bf16x8 bb[4];
#pragma unroll
    for(int nf = 0; nf < 4; nf++)
      bb[nf] = *(const bf16x8*)(vt + (size_t)(nf * 16 + lr) * 2048 + ks * 32 + lk8);
    if(ks <= ks0){
      int off = ((row0 * 128 + ks * 32 + lk8) * 2) ^ ((row0 & 7) << 4);
      bf16x8 af = *(const bf16x8*)((char*)S + off);
#pragma unroll
      for(int nf = 0; nf < 4; nf++)
        acc2[0][nf] = __builtin_amdgcn_mfma_f32_16x16x32_bf16(af, bb[nf], acc2[0][nf], 0, 0, 0);
    }
    {
      int off = ((row1 * 128 + ks * 32 + lk8) * 2) ^ ((row1 & 7) << 4);
      bf16x8 af = *(const bf16x8*)((char*)S + off);
#pragma unroll
      for(int nf = 0; nf < 4; nf++)
        acc2[1][nf] = __builtin_amdgcn_mfma_f32_16x16x32_bf16(af, bb[nf], acc2[1][nf], 0, 0, 0);
    }
  }
#pragma unroll
  for(int mi = 0; mi < 2; mi++){
    int Rm = (wid + mi * 4) * 16;
#pragma unroll
    for(int nf = 0; nf < 4; nf++)
#pragma unroll
      for(int r = 0; r < 4; r++){
        int grow = Rm + lq * 4 + r, gcol = nf * 16 + lr;
        yg[(size_t)grow * 1024 + gcol] = f2bf(acc2[mi][nf][r]);
      }
  }
}

// ---------------- launch ----------------
extern "C" void kernel_launch(void* const* d_in, const int* in_sizes, int n_in,
                              void* d_out, int out_size, void* d_ws, size_t ws_size,
                              hipStream_t stream)
{
  const float* X    = (const float*)d_in[0];
  const float* Wq   = (const float*)d_in[1];
  const float* Wk   = (const float*)d_in[2];
  const float* Wv   = (const float*)d_in[3];
  const float* Wc   = (const float*)d_in[4];
  const float* Ltri = (const float*)d_in[5];
  float* out = (float*)d_out;

  char* ws = (char*)d_ws;
  size_t off = 0;
  auto carve = [&](size_t bytes) -> char* {
    char* p = ws + off;
    off += (bytes + 255) & ~(size_t)255;
    return p;
  };
  u16* Xb   = (u16*)carve((size_t)4194304 * 2);
  u16* Wqb  = (u16*)carve((size_t)1048576 * 2);
  u16* Wkb  = (u16*)carve((size_t)1048576 * 2);
  u16* Wvb  = (u16*)carve((size_t)1048576 * 2);
  u16* Wcb  = (u16*)carve((size_t)1048576 * 2);
  u16* Wcpb = (u16*)carve((size_t)1048576 * 2);
  u16* Bmb  = (u16*)carve((size_t)65536 * 2);
  u16* Qb   = (u16*)carve((size_t)4194304 * 2);
  u16* Kb   = (u16*)carve((size_t)4194304 * 2);
  u16* Vb   = (u16*)carve((size_t)4194304 * 2);
  u16* VT   = (u16*)carve((size_t)4194304 * 2);
  float* Sc = (float*)carve((size_t)2097152 * 4);
  u16* Yb   = (u16*)carve((size_t)4194304 * 2);
  (void)in_sizes; (void)n_in; (void)out_size; (void)ws_size;

  prep_kernel<<<2064, 256, 0, stream>>>(X, Xb, Wq, Wqb, Wk, Wkb, Wv, Wvb, Wc, Wcb, Ltri, Bmb);
  qkv_gemm<<<dim3(32, 24), 256, 0, stream>>>(Xb, Wqb, Wkb, Wvb, Qb, Kb, Vb);
  state_fold<<<640, 256, 0, stream>>>(Kb, Vb, VT, Sc, Wcb, Bmb, Wcpb);
  chunk_attn<<<dim3(32, 16), 256, 0, stream>>>(Qb, Kb, VT, Sc, Yb);
  out_gemm<<<dim3(32, 8), 256, 0, stream>>>(Yb, Wcpb, out);
}